// Round 9
// baseline (257.684 us; speedup 1.0000x reference)
//
#include <hip/hip_runtime.h>

#define N_NODES 50000
#define N_EDGES 400000
#define DIM 128

typedef unsigned short u16;
typedef unsigned int   u32;
typedef __bf16 v8bf  __attribute__((ext_vector_type(8)));
typedef float  f32x4 __attribute__((ext_vector_type(4)));
typedef u16    u16x8 __attribute__((ext_vector_type(8)));

union BF8 { u16x8 u; v8bf b; };

__device__ __forceinline__ float bf2f(u16 u) {
    union { u32 i; float f; } v; v.i = ((u32)u) << 16; return v.f;
}
__device__ __forceinline__ u16 f2bf(float f) {
    union { float f; u32 i; } v; v.f = f; u32 u = v.i;
    return (u16)((u + 0x7FFFu + ((u >> 16) & 1u)) >> 16);  // RNE
}

// ---------------------------------------------------------------------------
// count + weight cast fused: blocks [0, EDGE_BLK) histogram dst;
// blocks [EDGE_BLK, EDGE_BLK+64) cast W1/W2 -> bf16.
// ---------------------------------------------------------------------------
#define EDGE_BLK ((N_EDGES + 255) / 256)     // 1563
__global__ __launch_bounds__(256) void count_cast_kernel(
    const int* __restrict__ edst, int* __restrict__ counts,
    const float* __restrict__ W1, const float* __restrict__ W2,
    u16* __restrict__ Wb1, u16* __restrict__ Wb2)
{
    int bid = blockIdx.x;
    if (bid < EDGE_BLK) {
        int e = bid * 256 + threadIdx.x;
        if (e >= N_EDGES) return;
        int dst = edst[e];
        if ((unsigned)dst >= N_NODES) return;
        atomicAdd(&counts[dst], 1);
    } else {
        int i = (bid - EDGE_BLK) * 256 + threadIdx.x;
        if (i < DIM * DIM) {
            Wb1[i] = f2bf(W1[i]);
            Wb2[i] = f2bf(W2[i]);
        }
    }
}

// ---------------------------------------------------------------------------
// Single-kernel exclusive scan: 1 block x 1024 threads, 49 counts/thread.
// Counts cached in registers (independent loads -> ILP); LDS Hillis-Steele
// over the 1024 partial sums; register-walk writeback of row_ptr + cursor.
// (Round-3 lesson: the single-block scan died on serial dependent global
//  loads, not on the algorithm — registers + independent loads fix it.)
// ---------------------------------------------------------------------------
#define SCAN_PER 49   // ceil(50000/1024)
__global__ __launch_bounds__(1024) void scan_one_kernel(
    const int* __restrict__ counts, int* __restrict__ row_ptr,
    int* __restrict__ cursor)
{
    __shared__ int sums[1024];
    const int t = threadIdx.x;
    const int begin = t * SCAN_PER;

    int local[SCAN_PER];
    int s = 0;
#pragma unroll
    for (int j = 0; j < SCAN_PER; ++j) {
        int i = begin + j;
        local[j] = (i < N_NODES) ? counts[i] : 0;
    }
#pragma unroll
    for (int j = 0; j < SCAN_PER; ++j) s += local[j];
    sums[t] = s;
    __syncthreads();

    for (int ofs = 1; ofs < 1024; ofs <<= 1) {
        int add = (t >= ofs) ? sums[t - ofs] : 0;
        __syncthreads();
        sums[t] += add;
        __syncthreads();
    }

    int off = sums[t] - s;   // exclusive prefix of this thread's chunk
#pragma unroll
    for (int j = 0; j < SCAN_PER; ++j) {
        int i = begin + j;
        if (i < N_NODES) {
            row_ptr[i] = off;
            cursor[i]  = off;
            off += local[j];
        }
    }
    if (t == 1023) row_ptr[N_NODES] = N_EDGES;
}

// ---------------------------------------------------------------------------
// bucket edges by destination (store src index)
// ---------------------------------------------------------------------------
__global__ __launch_bounds__(256) void bucket_kernel(
    const int* __restrict__ esrc, const int* __restrict__ edst,
    int* __restrict__ cursor, int* __restrict__ esorted)
{
    int e = blockIdx.x * 256 + threadIdx.x;
    if (e >= N_EDGES) return;
    int src = esrc[e], dst = edst[e];
    if ((unsigned)src >= N_NODES || (unsigned)dst >= N_NODES) return;
    int pos = atomicAdd(&cursor[dst], 1);
    esorted[pos] = src;
}

// ---------------------------------------------------------------------------
// fc1: h = relu(x @ W1^T + b1)  via bf16 MFMA 16x16x32, fp32 accumulate.
// ---------------------------------------------------------------------------
__global__ __launch_bounds__(256, 3) void fc1_mfma(
    const float* __restrict__ x, const u16* __restrict__ Wb,
    const float* __restrict__ b, u16* __restrict__ h)
{
    __shared__ u16 xs[64 * 136];
    const int t = threadIdx.x;
    const int wave = t >> 6, lane = t & 63, quad = lane >> 4, l15 = lane & 15;
    const int ch = wave >> 1, rh = wave & 1;
    const int row0 = blockIdx.x * 64;

    BF8 barr[4][4];
#pragma unroll
    for (int ct = 0; ct < 4; ++ct)
#pragma unroll
        for (int ks = 0; ks < 4; ++ks)
            barr[ct][ks].u = *(const u16x8*)(
                Wb + (size_t)(ch * 64 + ct * 16 + l15) * DIM + ks * 32 + quad * 8);

    {
        int srow = t >> 2, k0 = (t & 3) * 32;
        int grow = row0 + srow; if (grow >= N_NODES) grow = N_NODES - 1;
        const float* xp = x + (size_t)grow * DIM + k0;
#pragma unroll
        for (int j = 0; j < 4; ++j) {
            float4 f0 = *(const float4*)(xp + j * 8);
            float4 f1 = *(const float4*)(xp + j * 8 + 4);
            u16x8 p;
            p[0] = f2bf(f0.x); p[1] = f2bf(f0.y); p[2] = f2bf(f0.z); p[3] = f2bf(f0.w);
            p[4] = f2bf(f1.x); p[5] = f2bf(f1.y); p[6] = f2bf(f1.z); p[7] = f2bf(f1.w);
            *(u16x8*)&xs[srow * 136 + k0 + j * 8] = p;
        }
    }

    f32x4 acc[2][4];
#pragma unroll
    for (int ct = 0; ct < 4; ++ct) {
        float bv = b[ch * 64 + ct * 16 + l15];
        acc[0][ct] = (f32x4){bv, bv, bv, bv};
        acc[1][ct] = (f32x4){bv, bv, bv, bv};
    }
    __syncthreads();

#pragma unroll
    for (int ks = 0; ks < 4; ++ks) {
        BF8 a0, a1;
        a0.u = *(const u16x8*)&xs[(rh * 32 +  0 + l15) * 136 + ks * 32 + quad * 8];
        a1.u = *(const u16x8*)&xs[(rh * 32 + 16 + l15) * 136 + ks * 32 + quad * 8];
#pragma unroll
        for (int ct = 0; ct < 4; ++ct) {
            acc[0][ct] = __builtin_amdgcn_mfma_f32_16x16x32_bf16(
                a0.b, barr[ct][ks].b, acc[0][ct], 0, 0, 0);
            acc[1][ct] = __builtin_amdgcn_mfma_f32_16x16x32_bf16(
                a1.b, barr[ct][ks].b, acc[1][ct], 0, 0, 0);
        }
    }

#pragma unroll
    for (int rt = 0; rt < 2; ++rt)
#pragma unroll
        for (int i = 0; i < 4; ++i) {
            int row = row0 + rh * 32 + rt * 16 + quad * 4 + i;
            if (row < N_NODES) {
#pragma unroll
                for (int ct = 0; ct < 4; ++ct) {
                    int col = ch * 64 + ct * 16 + l15;
                    h[(size_t)row * DIM + col] = f2bf(fmaxf(acc[rt][ct][i], 0.f));
                }
            }
        }
}

// ---------------------------------------------------------------------------
// aggregate: z[n] = mean(h[src in in(n)]) + h[n]   (h,z bf16; fp32 accumulate)
// 4 waves/block, one wave per node, lane owns 2 dims, MLP 8.
// ---------------------------------------------------------------------------
__global__ __launch_bounds__(256) void aggregate_kernel(
    const int* __restrict__ row_ptr, const int* __restrict__ esorted,
    const u16* __restrict__ h, u16* __restrict__ z)
{
    const int wave = threadIdx.x >> 6;
    const int lane = threadIdx.x & 63;
    const int n = blockIdx.x * 4 + wave;
    if (n >= N_NODES) return;

    const int start = row_ptr[n];
    const int end   = row_ptr[n + 1];

    float a0 = 0.f, a1 = 0.f;
    int e = start;
    for (; e + 8 <= end; e += 8) {
        int s0 = esorted[e + 0], s1 = esorted[e + 1];
        int s2 = esorted[e + 2], s3 = esorted[e + 3];
        int s4 = esorted[e + 4], s5 = esorted[e + 5];
        int s6 = esorted[e + 6], s7 = esorted[e + 7];
        u32 v0 = *(const u32*)(h + (size_t)s0 * DIM + lane * 2);
        u32 v1 = *(const u32*)(h + (size_t)s1 * DIM + lane * 2);
        u32 v2 = *(const u32*)(h + (size_t)s2 * DIM + lane * 2);
        u32 v3 = *(const u32*)(h + (size_t)s3 * DIM + lane * 2);
        u32 v4 = *(const u32*)(h + (size_t)s4 * DIM + lane * 2);
        u32 v5 = *(const u32*)(h + (size_t)s5 * DIM + lane * 2);
        u32 v6 = *(const u32*)(h + (size_t)s6 * DIM + lane * 2);
        u32 v7 = *(const u32*)(h + (size_t)s7 * DIM + lane * 2);
        a0 += bf2f((u16)v0); a1 += bf2f((u16)(v0 >> 16));
        a0 += bf2f((u16)v1); a1 += bf2f((u16)(v1 >> 16));
        a0 += bf2f((u16)v2); a1 += bf2f((u16)(v2 >> 16));
        a0 += bf2f((u16)v3); a1 += bf2f((u16)(v3 >> 16));
        a0 += bf2f((u16)v4); a1 += bf2f((u16)(v4 >> 16));
        a0 += bf2f((u16)v5); a1 += bf2f((u16)(v5 >> 16));
        a0 += bf2f((u16)v6); a1 += bf2f((u16)(v6 >> 16));
        a0 += bf2f((u16)v7); a1 += bf2f((u16)(v7 >> 16));
    }
    for (; e + 4 <= end; e += 4) {
        int s0 = esorted[e + 0], s1 = esorted[e + 1];
        int s2 = esorted[e + 2], s3 = esorted[e + 3];
        u32 v0 = *(const u32*)(h + (size_t)s0 * DIM + lane * 2);
        u32 v1 = *(const u32*)(h + (size_t)s1 * DIM + lane * 2);
        u32 v2 = *(const u32*)(h + (size_t)s2 * DIM + lane * 2);
        u32 v3 = *(const u32*)(h + (size_t)s3 * DIM + lane * 2);
        a0 += bf2f((u16)v0); a1 += bf2f((u16)(v0 >> 16));
        a0 += bf2f((u16)v1); a1 += bf2f((u16)(v1 >> 16));
        a0 += bf2f((u16)v2); a1 += bf2f((u16)(v2 >> 16));
        a0 += bf2f((u16)v3); a1 += bf2f((u16)(v3 >> 16));
    }
    for (; e < end; ++e) {
        u32 v = *(const u32*)(h + (size_t)esorted[e] * DIM + lane * 2);
        a0 += bf2f((u16)v); a1 += bf2f((u16)(v >> 16));
    }

    int deg = end - start;
    float inv = (deg > 0) ? 1.f / (float)deg : 1.f;
    u32 r = *(const u32*)(h + (size_t)n * DIM + lane * 2);
    float z0 = a0 * inv + bf2f((u16)r);
    float z1 = a1 * inv + bf2f((u16)(r >> 16));
    u32 p = (u32)f2bf(z0) | ((u32)f2bf(z1) << 16);
    *(u32*)(z + (size_t)n * DIM + lane * 2) = p;
}

// ---------------------------------------------------------------------------
// fc2: out = z @ W2^T + b2 (z bf16, out fp32)
// ---------------------------------------------------------------------------
__global__ __launch_bounds__(256, 3) void fc2_mfma(
    const u16* __restrict__ z, const u16* __restrict__ Wb,
    const float* __restrict__ b, float* __restrict__ out)
{
    __shared__ u16 xs[64 * 136];
    const int t = threadIdx.x;
    const int wave = t >> 6, lane = t & 63, quad = lane >> 4, l15 = lane & 15;
    const int ch = wave >> 1, rh = wave & 1;
    const int row0 = blockIdx.x * 64;

    BF8 barr[4][4];
#pragma unroll
    for (int ct = 0; ct < 4; ++ct)
#pragma unroll
        for (int ks = 0; ks < 4; ++ks)
            barr[ct][ks].u = *(const u16x8*)(
                Wb + (size_t)(ch * 64 + ct * 16 + l15) * DIM + ks * 32 + quad * 8);

    {
        int srow = t >> 1, k0 = (t & 1) * 64;
        int grow = row0 + srow; if (grow >= N_NODES) grow = N_NODES - 1;
        const u16* zp = z + (size_t)grow * DIM + k0;
#pragma unroll
        for (int j = 0; j < 8; ++j)
            *(u16x8*)&xs[srow * 136 + k0 + j * 8] = *(const u16x8*)(zp + j * 8);
    }

    f32x4 acc[2][4];
#pragma unroll
    for (int ct = 0; ct < 4; ++ct) {
        float bv = b[ch * 64 + ct * 16 + l15];
        acc[0][ct] = (f32x4){bv, bv, bv, bv};
        acc[1][ct] = (f32x4){bv, bv, bv, bv};
    }
    __syncthreads();

#pragma unroll
    for (int ks = 0; ks < 4; ++ks) {
        BF8 a0, a1;
        a0.u = *(const u16x8*)&xs[(rh * 32 +  0 + l15) * 136 + ks * 32 + quad * 8];
        a1.u = *(const u16x8*)&xs[(rh * 32 + 16 + l15) * 136 + ks * 32 + quad * 8];
#pragma unroll
        for (int ct = 0; ct < 4; ++ct) {
            acc[0][ct] = __builtin_amdgcn_mfma_f32_16x16x32_bf16(
                a0.b, barr[ct][ks].b, acc[0][ct], 0, 0, 0);
            acc[1][ct] = __builtin_amdgcn_mfma_f32_16x16x32_bf16(
                a1.b, barr[ct][ks].b, acc[1][ct], 0, 0, 0);
        }
    }

#pragma unroll
    for (int rt = 0; rt < 2; ++rt)
#pragma unroll
        for (int i = 0; i < 4; ++i) {
            int row = row0 + rh * 32 + rt * 16 + quad * 4 + i;
            if (row < N_NODES) {
#pragma unroll
                for (int ct = 0; ct < 4; ++ct) {
                    int col = ch * 64 + ct * 16 + l15;
                    out[(size_t)row * DIM + col] = acc[rt][ct][i];
                }
            }
        }
}

extern "C" void kernel_launch(void* const* d_in, const int* in_sizes, int n_in,
                              void* d_out, int out_size, void* d_ws, size_t ws_size,
                              hipStream_t stream)
{
    const float* x  = (const float*)d_in[0];
    const int*   ei = (const int*)d_in[1];   // [2][E] int32
    const float* W1 = (const float*)d_in[2];
    const float* b1 = (const float*)d_in[3];
    const float* W2 = (const float*)d_in[4];
    const float* b2 = (const float*)d_in[5];
    float* out = (float*)d_out;

    const int* esrc = ei;
    const int* edst = ei + N_EDGES;

    char* ws = (char*)d_ws;
    size_t off = 0;
    u16* h        = (u16*)(ws + off); off += (size_t)N_NODES * DIM * 2;   // 12.8 MB
    u16* z        = (u16*)(ws + off); off += (size_t)N_NODES * DIM * 2;   // 12.8 MB
    u16* Wb1      = (u16*)(ws + off); off += (size_t)DIM * DIM * 2;       // 32 KB
    u16* Wb2      = (u16*)(ws + off); off += (size_t)DIM * DIM * 2;       // 32 KB
    int* counts   = (int*)(ws + off); off += (size_t)N_NODES * 4;
    int* row_ptr  = (int*)(ws + off); off += (size_t)(N_NODES + 1) * 4;
    int* cursor   = (int*)(ws + off); off += (size_t)N_NODES * 4;
    int* esorted  = (int*)(ws + off); off += (size_t)N_EDGES * 4;

    hipMemsetAsync(counts, 0, (size_t)N_NODES * 4, stream);
    count_cast_kernel<<<EDGE_BLK + 64, 256, 0, stream>>>(
        edst, counts, W1, W2, Wb1, Wb2);
    scan_one_kernel<<<1, 1024, 0, stream>>>(counts, row_ptr, cursor);
    bucket_kernel<<<(N_EDGES + 255) / 256, 256, 0, stream>>>(
        esrc, edst, cursor, esorted);

    fc1_mfma<<<(N_NODES + 63) / 64, 256, 0, stream>>>(x, Wb1, b1, h);
    aggregate_kernel<<<(N_NODES + 3) / 4, 256, 0, stream>>>(
        row_ptr, esorted, h, z);
    fc2_mfma<<<(N_NODES + 63) / 64, 256, 0, stream>>>(z, Wb2, b2, out);
}

// Round 10
// 178.577 us; speedup vs baseline: 1.4430x; 1.4430x over previous
//
#include <hip/hip_runtime.h>

#define N_NODES 50000
#define N_EDGES 400000
#define DIM 128
#define N_SCAN_BLK ((N_NODES + 255) / 256)   // 196
#define BUCKET_BLK ((N_EDGES + 255) / 256)   // 1563
#define FC1_BLK ((N_NODES + 63) / 64)        // 782

typedef unsigned short u16;
typedef unsigned int   u32;
typedef __bf16 v8bf  __attribute__((ext_vector_type(8)));
typedef float  f32x4 __attribute__((ext_vector_type(4)));
typedef u16    u16x8 __attribute__((ext_vector_type(8)));

union BF8 { u16x8 u; v8bf b; };

__device__ __forceinline__ float bf2f(u16 u) {
    union { u32 i; float f; } v; v.i = ((u32)u) << 16; return v.f;
}
__device__ __forceinline__ u16 f2bf(float f) {
    union { float f; u32 i; } v; v.f = f; u32 u = v.i;
    return (u16)((u + 0x7FFFu + ((u >> 16) & 1u)) >> 16);  // RNE
}

// ---------------------------------------------------------------------------
// count + weight cast fused: blocks [0, BUCKET_BLK) histogram dst;
// blocks [BUCKET_BLK, BUCKET_BLK+64) cast W1/W2 -> bf16.
// ---------------------------------------------------------------------------
__global__ __launch_bounds__(256) void count_cast_kernel(
    const int* __restrict__ edst, int* __restrict__ counts,
    const float* __restrict__ W1, const float* __restrict__ W2,
    u16* __restrict__ Wb1, u16* __restrict__ Wb2)
{
    int bid = blockIdx.x;
    if (bid < BUCKET_BLK) {
        int e = bid * 256 + threadIdx.x;
        if (e >= N_EDGES) return;
        int dst = edst[e];
        if ((unsigned)dst >= N_NODES) return;
        atomicAdd(&counts[dst], 1);
    } else {
        int i = (bid - BUCKET_BLK) * 256 + threadIdx.x;
        if (i < DIM * DIM) {
            Wb1[i] = f2bf(W1[i]);
            Wb2[i] = f2bf(W2[i]);
        }
    }
}

// ---------------------------------------------------------------------------
// per-block exclusive scan (256 counters/block) + block totals
// ---------------------------------------------------------------------------
__global__ __launch_bounds__(256) void scan_blocks_kernel(
    const int* __restrict__ counts, int* __restrict__ row_ptr,
    int* __restrict__ bsum)
{
    __shared__ int tmp[256];
    const int t = threadIdx.x;
    const int i = blockIdx.x * 256 + t;
    int v = (i < N_NODES) ? counts[i] : 0;
    tmp[t] = v;
    __syncthreads();
#pragma unroll
    for (int ofs = 1; ofs < 256; ofs <<= 1) {
        int add = (t >= ofs) ? tmp[t - ofs] : 0;
        __syncthreads();
        tmp[t] += add;
        __syncthreads();
    }
    if (i < N_NODES) row_ptr[i] = tmp[t] - v;
    if (t == 255) bsum[blockIdx.x] = tmp[255];
}

// ---------------------------------------------------------------------------
// fixup with redundant top-scan: every block scans the 196 block sums in LDS
// (tiny), picks its own offset, fixes its 256 rows. Merges scan_top+fixup.
// ---------------------------------------------------------------------------
__global__ __launch_bounds__(256) void scan_fixup2_kernel(
    const int* __restrict__ bsum, int* __restrict__ row_ptr,
    int* __restrict__ cursor)
{
    __shared__ int tmp[256];
    __shared__ int ex[256];
    const int t = threadIdx.x;
    int v = (t < N_SCAN_BLK) ? bsum[t] : 0;
    tmp[t] = v;
    __syncthreads();
#pragma unroll
    for (int ofs = 1; ofs < 256; ofs <<= 1) {
        int add = (t >= ofs) ? tmp[t - ofs] : 0;
        __syncthreads();
        tmp[t] += add;
        __syncthreads();
    }
    ex[t] = tmp[t] - v;      // exclusive prefix
    __syncthreads();

    int boff = ex[blockIdx.x];
    int i = blockIdx.x * 256 + t;
    if (i < N_NODES) {
        int r = row_ptr[i] + boff;
        row_ptr[i] = r;
        cursor[i]  = r;
    }
    if (i == 0) row_ptr[N_NODES] = N_EDGES;
}

// ---------------------------------------------------------------------------
// bucket + fc1 fused: blocks [0, BUCKET_BLK) scatter edges into CSR;
// blocks [BUCKET_BLK, BUCKET_BLK+FC1_BLK) run the fc1 MFMA tile.
// bucket is latency-bound (atomics), fc1 is MFMA-bound -> co-scheduling
// overlaps them (combined ~= max, not sum).
// ---------------------------------------------------------------------------
__global__ __launch_bounds__(256, 3) void bucket_fc1_kernel(
    const int* __restrict__ esrc, const int* __restrict__ edst,
    int* __restrict__ cursor, int* __restrict__ esorted,
    const float* __restrict__ x, const u16* __restrict__ Wb,
    const float* __restrict__ b, u16* __restrict__ h)
{
    __shared__ u16 xs[64 * 136];
    const int bid = blockIdx.x;

    if (bid < BUCKET_BLK) {
        int e = bid * 256 + threadIdx.x;
        if (e < N_EDGES) {
            int src = esrc[e], dst = edst[e];
            if ((unsigned)src < N_NODES && (unsigned)dst < N_NODES) {
                int pos = atomicAdd(&cursor[dst], 1);
                esorted[pos] = src;
            }
        }
        return;
    }

    // ---- fc1 tile ----
    const int t = threadIdx.x;
    const int wave = t >> 6, lane = t & 63, quad = lane >> 4, l15 = lane & 15;
    const int ch = wave >> 1, rh = wave & 1;
    const int row0 = (bid - BUCKET_BLK) * 64;

    BF8 barr[4][4];
#pragma unroll
    for (int ct = 0; ct < 4; ++ct)
#pragma unroll
        for (int ks = 0; ks < 4; ++ks)
            barr[ct][ks].u = *(const u16x8*)(
                Wb + (size_t)(ch * 64 + ct * 16 + l15) * DIM + ks * 32 + quad * 8);

    {
        int srow = t >> 2, k0 = (t & 3) * 32;
        int grow = row0 + srow; if (grow >= N_NODES) grow = N_NODES - 1;
        const float* xp = x + (size_t)grow * DIM + k0;
#pragma unroll
        for (int j = 0; j < 4; ++j) {
            float4 f0 = *(const float4*)(xp + j * 8);
            float4 f1 = *(const float4*)(xp + j * 8 + 4);
            u16x8 p;
            p[0] = f2bf(f0.x); p[1] = f2bf(f0.y); p[2] = f2bf(f0.z); p[3] = f2bf(f0.w);
            p[4] = f2bf(f1.x); p[5] = f2bf(f1.y); p[6] = f2bf(f1.z); p[7] = f2bf(f1.w);
            *(u16x8*)&xs[srow * 136 + k0 + j * 8] = p;
        }
    }

    f32x4 acc[2][4];
#pragma unroll
    for (int ct = 0; ct < 4; ++ct) {
        float bv = b[ch * 64 + ct * 16 + l15];
        acc[0][ct] = (f32x4){bv, bv, bv, bv};
        acc[1][ct] = (f32x4){bv, bv, bv, bv};
    }
    __syncthreads();

#pragma unroll
    for (int ks = 0; ks < 4; ++ks) {
        BF8 a0, a1;
        a0.u = *(const u16x8*)&xs[(rh * 32 +  0 + l15) * 136 + ks * 32 + quad * 8];
        a1.u = *(const u16x8*)&xs[(rh * 32 + 16 + l15) * 136 + ks * 32 + quad * 8];
#pragma unroll
        for (int ct = 0; ct < 4; ++ct) {
            acc[0][ct] = __builtin_amdgcn_mfma_f32_16x16x32_bf16(
                a0.b, barr[ct][ks].b, acc[0][ct], 0, 0, 0);
            acc[1][ct] = __builtin_amdgcn_mfma_f32_16x16x32_bf16(
                a1.b, barr[ct][ks].b, acc[1][ct], 0, 0, 0);
        }
    }

#pragma unroll
    for (int rt = 0; rt < 2; ++rt)
#pragma unroll
        for (int i = 0; i < 4; ++i) {
            int row = row0 + rh * 32 + rt * 16 + quad * 4 + i;
            if (row < N_NODES) {
#pragma unroll
                for (int ct = 0; ct < 4; ++ct) {
                    int col = ch * 64 + ct * 16 + l15;
                    h[(size_t)row * DIM + col] = f2bf(fmaxf(acc[rt][ct][i], 0.f));
                }
            }
        }
}

// ---------------------------------------------------------------------------
// aggregate: z[n] = mean(h[src in in(n)]) + h[n]   (h,z bf16; fp32 accumulate)
// 4 waves/block, one wave per node, lane owns 2 dims, MLP 8.
// ---------------------------------------------------------------------------
__global__ __launch_bounds__(256) void aggregate_kernel(
    const int* __restrict__ row_ptr, const int* __restrict__ esorted,
    const u16* __restrict__ h, u16* __restrict__ z)
{
    const int wave = threadIdx.x >> 6;
    const int lane = threadIdx.x & 63;
    const int n = blockIdx.x * 4 + wave;
    if (n >= N_NODES) return;

    const int start = row_ptr[n];
    const int end   = row_ptr[n + 1];

    float a0 = 0.f, a1 = 0.f;
    int e = start;
    for (; e + 8 <= end; e += 8) {
        int s0 = esorted[e + 0], s1 = esorted[e + 1];
        int s2 = esorted[e + 2], s3 = esorted[e + 3];
        int s4 = esorted[e + 4], s5 = esorted[e + 5];
        int s6 = esorted[e + 6], s7 = esorted[e + 7];
        u32 v0 = *(const u32*)(h + (size_t)s0 * DIM + lane * 2);
        u32 v1 = *(const u32*)(h + (size_t)s1 * DIM + lane * 2);
        u32 v2 = *(const u32*)(h + (size_t)s2 * DIM + lane * 2);
        u32 v3 = *(const u32*)(h + (size_t)s3 * DIM + lane * 2);
        u32 v4 = *(const u32*)(h + (size_t)s4 * DIM + lane * 2);
        u32 v5 = *(const u32*)(h + (size_t)s5 * DIM + lane * 2);
        u32 v6 = *(const u32*)(h + (size_t)s6 * DIM + lane * 2);
        u32 v7 = *(const u32*)(h + (size_t)s7 * DIM + lane * 2);
        a0 += bf2f((u16)v0); a1 += bf2f((u16)(v0 >> 16));
        a0 += bf2f((u16)v1); a1 += bf2f((u16)(v1 >> 16));
        a0 += bf2f((u16)v2); a1 += bf2f((u16)(v2 >> 16));
        a0 += bf2f((u16)v3); a1 += bf2f((u16)(v3 >> 16));
        a0 += bf2f((u16)v4); a1 += bf2f((u16)(v4 >> 16));
        a0 += bf2f((u16)v5); a1 += bf2f((u16)(v5 >> 16));
        a0 += bf2f((u16)v6); a1 += bf2f((u16)(v6 >> 16));
        a0 += bf2f((u16)v7); a1 += bf2f((u16)(v7 >> 16));
    }
    for (; e + 4 <= end; e += 4) {
        int s0 = esorted[e + 0], s1 = esorted[e + 1];
        int s2 = esorted[e + 2], s3 = esorted[e + 3];
        u32 v0 = *(const u32*)(h + (size_t)s0 * DIM + lane * 2);
        u32 v1 = *(const u32*)(h + (size_t)s1 * DIM + lane * 2);
        u32 v2 = *(const u32*)(h + (size_t)s2 * DIM + lane * 2);
        u32 v3 = *(const u32*)(h + (size_t)s3 * DIM + lane * 2);
        a0 += bf2f((u16)v0); a1 += bf2f((u16)(v0 >> 16));
        a0 += bf2f((u16)v1); a1 += bf2f((u16)(v1 >> 16));
        a0 += bf2f((u16)v2); a1 += bf2f((u16)(v2 >> 16));
        a0 += bf2f((u16)v3); a1 += bf2f((u16)(v3 >> 16));
    }
    for (; e < end; ++e) {
        u32 v = *(const u32*)(h + (size_t)esorted[e] * DIM + lane * 2);
        a0 += bf2f((u16)v); a1 += bf2f((u16)(v >> 16));
    }

    int deg = end - start;
    float inv = (deg > 0) ? 1.f / (float)deg : 1.f;
    u32 r = *(const u32*)(h + (size_t)n * DIM + lane * 2);
    float z0 = a0 * inv + bf2f((u16)r);
    float z1 = a1 * inv + bf2f((u16)(r >> 16));
    u32 p = (u32)f2bf(z0) | ((u32)f2bf(z1) << 16);
    *(u32*)(z + (size_t)n * DIM + lane * 2) = p;
}

// ---------------------------------------------------------------------------
// fc2: out = z @ W2^T + b2 (z bf16, out fp32)
// ---------------------------------------------------------------------------
__global__ __launch_bounds__(256, 3) void fc2_mfma(
    const u16* __restrict__ z, const u16* __restrict__ Wb,
    const float* __restrict__ b, float* __restrict__ out)
{
    __shared__ u16 xs[64 * 136];
    const int t = threadIdx.x;
    const int wave = t >> 6, lane = t & 63, quad = lane >> 4, l15 = lane & 15;
    const int ch = wave >> 1, rh = wave & 1;
    const int row0 = blockIdx.x * 64;

    BF8 barr[4][4];
#pragma unroll
    for (int ct = 0; ct < 4; ++ct)
#pragma unroll
        for (int ks = 0; ks < 4; ++ks)
            barr[ct][ks].u = *(const u16x8*)(
                Wb + (size_t)(ch * 64 + ct * 16 + l15) * DIM + ks * 32 + quad * 8);

    {
        int srow = t >> 1, k0 = (t & 1) * 64;
        int grow = row0 + srow; if (grow >= N_NODES) grow = N_NODES - 1;
        const u16* zp = z + (size_t)grow * DIM + k0;
#pragma unroll
        for (int j = 0; j < 8; ++j)
            *(u16x8*)&xs[srow * 136 + k0 + j * 8] = *(const u16x8*)(zp + j * 8);
    }

    f32x4 acc[2][4];
#pragma unroll
    for (int ct = 0; ct < 4; ++ct) {
        float bv = b[ch * 64 + ct * 16 + l15];
        acc[0][ct] = (f32x4){bv, bv, bv, bv};
        acc[1][ct] = (f32x4){bv, bv, bv, bv};
    }
    __syncthreads();

#pragma unroll
    for (int ks = 0; ks < 4; ++ks) {
        BF8 a0, a1;
        a0.u = *(const u16x8*)&xs[(rh * 32 +  0 + l15) * 136 + ks * 32 + quad * 8];
        a1.u = *(const u16x8*)&xs[(rh * 32 + 16 + l15) * 136 + ks * 32 + quad * 8];
#pragma unroll
        for (int ct = 0; ct < 4; ++ct) {
            acc[0][ct] = __builtin_amdgcn_mfma_f32_16x16x32_bf16(
                a0.b, barr[ct][ks].b, acc[0][ct], 0, 0, 0);
            acc[1][ct] = __builtin_amdgcn_mfma_f32_16x16x32_bf16(
                a1.b, barr[ct][ks].b, acc[1][ct], 0, 0, 0);
        }
    }

#pragma unroll
    for (int rt = 0; rt < 2; ++rt)
#pragma unroll
        for (int i = 0; i < 4; ++i) {
            int row = row0 + rh * 32 + rt * 16 + quad * 4 + i;
            if (row < N_NODES) {
#pragma unroll
                for (int ct = 0; ct < 4; ++ct) {
                    int col = ch * 64 + ct * 16 + l15;
                    out[(size_t)row * DIM + col] = acc[rt][ct][i];
                }
            }
        }
}

extern "C" void kernel_launch(void* const* d_in, const int* in_sizes, int n_in,
                              void* d_out, int out_size, void* d_ws, size_t ws_size,
                              hipStream_t stream)
{
    const float* x  = (const float*)d_in[0];
    const int*   ei = (const int*)d_in[1];   // [2][E] int32
    const float* W1 = (const float*)d_in[2];
    const float* b1 = (const float*)d_in[3];
    const float* W2 = (const float*)d_in[4];
    const float* b2 = (const float*)d_in[5];
    float* out = (float*)d_out;

    const int* esrc = ei;
    const int* edst = ei + N_EDGES;

    char* ws = (char*)d_ws;
    size_t off = 0;
    u16* h        = (u16*)(ws + off); off += (size_t)N_NODES * DIM * 2;   // 12.8 MB
    u16* z        = (u16*)(ws + off); off += (size_t)N_NODES * DIM * 2;   // 12.8 MB
    u16* Wb1      = (u16*)(ws + off); off += (size_t)DIM * DIM * 2;       // 32 KB
    u16* Wb2      = (u16*)(ws + off); off += (size_t)DIM * DIM * 2;       // 32 KB
    int* counts   = (int*)(ws + off); off += (size_t)N_NODES * 4;
    int* row_ptr  = (int*)(ws + off); off += (size_t)(N_NODES + 1) * 4;
    int* cursor   = (int*)(ws + off); off += (size_t)N_NODES * 4;
    int* esorted  = (int*)(ws + off); off += (size_t)N_EDGES * 4;
    int* bsum     = (int*)(ws + off); off += (size_t)N_SCAN_BLK * 4;

    hipMemsetAsync(counts, 0, (size_t)N_NODES * 4, stream);
    count_cast_kernel<<<BUCKET_BLK + 64, 256, 0, stream>>>(
        edst, counts, W1, W2, Wb1, Wb2);
    scan_blocks_kernel<<<N_SCAN_BLK, 256, 0, stream>>>(counts, row_ptr, bsum);
    scan_fixup2_kernel<<<N_SCAN_BLK, 256, 0, stream>>>(bsum, row_ptr, cursor);
    bucket_fc1_kernel<<<BUCKET_BLK + FC1_BLK, 256, 0, stream>>>(
        esrc, edst, cursor, esorted, x, Wb1, b1, h);
    aggregate_kernel<<<(N_NODES + 3) / 4, 256, 0, stream>>>(
        row_ptr, esorted, h, z);
    fc2_mfma<<<(N_NODES + 63) / 64, 256, 0, stream>>>(z, Wb2, b2, out);
}